// Round 7
// baseline (55.501 us; speedup 1.0000x reference)
//
#include <hip/hip_runtime.h>

// AttentionHead: B=4, S=4096, D=64, fp32 in/out.
// R7: barrier-free bf16 flash attention. Prep writes K/V^T in MFMA-fragment
// order (1KB blocks, lane l's u16x8 at base+l*16); main loop reads operand
// fragments straight from L2 with global_load_dwordx4 — no LDS staging, no
// __syncthreads, waves fully independent. Softmax/pack identical to R6.

#define BATCH 4
#define SEQ   4096
#define DIM   64
#define KVB   64
#define NQ    16384                  // BATCH*SEQ
#define QSCALE 0.18033688011112042f  // (1/sqrt(64)) * log2(e); all exps are exp2

typedef float f32x16 __attribute__((ext_vector_type(16)));
typedef unsigned short u16x8 __attribute__((ext_vector_type(8)));
typedef unsigned int   u32x4 __attribute__((ext_vector_type(4)));
typedef unsigned int   u32x2 __attribute__((ext_vector_type(2)));

#define MFMA32(a, b, c) __builtin_amdgcn_mfma_f32_32x32x16_bf16((a), (b), (c), 0, 0, 0)
#define EXP2F(x) __builtin_amdgcn_exp2f(x)

__device__ __forceinline__ void plswap(unsigned int& a, unsigned int& b) {
  u32x2 r = __builtin_amdgcn_permlane32_swap(a, b, false, false);
  a = r[0]; b = r[1];
}
__device__ __forceinline__ void xswap32f(float x, float& a, float& b) {
  unsigned int u = __float_as_uint(x), v = u;
  plswap(u, v);
  a = __uint_as_float(u); b = __uint_as_float(v);
}

__device__ __forceinline__ unsigned short f2bf(float x) {
  unsigned int u = __float_as_uint(x);
  return (unsigned short)((u + 0x7fffu + ((u >> 16) & 1u)) >> 16);   // RNE
}
__device__ __forceinline__ unsigned int cvtpk(float a, float b) {  // lo=a, hi=b
  unsigned int r;
  asm("v_cvt_pk_bf16_f32 %0, %1, %2" : "=v"(r) : "v"(a), "v"(b));
  return r;
}

// ---------------- prep: K,V -> fragment-ordered bf16 ------------------------
// Kf block (b, kb32, ch): 512 elems; elem l*8+j = K[b][kb32*32+(l&31)][ch*16+(l>>5)*8+j]
// Vf block (b, kb64, dh, ks): elem l*8+j = V[b][kb64*64+ks*16+(l>>5)*8+j][dh*32+(l&31)]
__global__ __launch_bounds__(256) void prep_kernel(
    const float* __restrict__ K, const float* __restrict__ V,
    unsigned short* __restrict__ Kf, unsigned short* __restrict__ Vf) {
  __shared__ float tk[64][65];
  __shared__ float tv[64][65];
  const int t = threadIdx.x;
  const int b = blockIdx.x >> 6;
  const int s0 = (blockIdx.x & 63) << 6;
  #pragma unroll
  for (int r = 0; r < 4; ++r) {
    const int s_loc = r * 16 + (t >> 4);
    const int d0 = (t & 15) << 2;
    const long base = ((long)b * SEQ + s0 + s_loc) * DIM + d0;
    const float4 kv = *(const float4*)(K + base);
    const float4 vv = *(const float4*)(V + base);
    tk[s_loc][d0 + 0] = kv.x; tk[s_loc][d0 + 1] = kv.y;
    tk[s_loc][d0 + 2] = kv.z; tk[s_loc][d0 + 3] = kv.w;
    tv[s_loc][d0 + 0] = vv.x; tv[s_loc][d0 + 1] = vv.y;
    tv[s_loc][d0 + 2] = vv.z; tv[s_loc][d0 + 3] = vv.w;
  }
  __syncthreads();
  const int l  = t >> 2;           // 0..63 (fragment lane)
  const int j0 = (t & 3) << 1;     // 0,2,4,6
  const int l5 = l & 31, b5 = l >> 5;
  #pragma unroll
  for (int kh = 0; kh < 2; ++kh) {
    #pragma unroll
    for (int ch = 0; ch < 4; ++ch) {
      const int key = kh * 32 + l5;
      const int d   = ch * 16 + b5 * 8 + j0;
      ushort2 w;
      w.x = f2bf(tk[key][d]);
      w.y = f2bf(tk[key][d + 1]);
      const long kb32 = (s0 >> 5) + kh;
      const long off = (((long)b * 128 + kb32) * 4 + ch) * 512 + 2 * t;
      *(ushort2*)(Kf + off) = w;
    }
  }
  #pragma unroll
  for (int dh = 0; dh < 2; ++dh) {
    #pragma unroll
    for (int ks = 0; ks < 4; ++ks) {
      const int key0 = ks * 16 + b5 * 8 + j0;
      const int d    = dh * 32 + l5;
      ushort2 w;
      w.x = f2bf(tv[key0][d]);
      w.y = f2bf(tv[key0 + 1][d]);
      const long kb64 = (s0 >> 6);
      const long off = ((((long)b * 64 + kb64) * 2 + dh) * 4 + ks) * 512 + 2 * t;
      *(ushort2*)(Vf + off) = w;
    }
  }
}

// ---------------- attention main kernel (barrier-free) ----------------------
template<int NS>
__global__ __launch_bounds__(256, 4) void attn_kernel(
    const float* __restrict__ Q,
    const unsigned short* __restrict__ Kf, const unsigned short* __restrict__ Vf,
    float* __restrict__ Opart, float* __restrict__ Mpart, float* __restrict__ Lpart) {

  __shared__ __align__(16) float tb[4][2048];   // epilogue transpose only, 32 KB

  constexpr int SPL = SEQ / NS;
  constexpr int NT  = SPL / KVB;
  constexpr int NWG = 4 * NS * 32;
  constexpr int CPX = NWG / 8;

  const int raw = blockIdx.x;
  const int bid = (raw & 7) * CPX + (raw >> 3);   // XCD-contiguous, bijective
  const int b     = bid / (NS * 32);
  const int rem   = bid % (NS * 32);
  const int split = rem >> 5;
  const int qblk  = rem & 31;

  const int tid  = threadIdx.x;
  const int wave = tid >> 6;
  const int lane = tid & 63;
  const int l5   = lane & 31;
  const int b5   = lane >> 5;

  const int qrow0 = qblk * 128 + wave * 32;
  const int kv0   = split * SPL;

  // ---- Q fragments: q row = l5; frag[ch] elem j <-> d = 16*ch + 8*b5 + j ----
  u16x8 qh[4];
  {
    const float* qp = Q + ((long)b * SEQ + qrow0 + l5) * DIM;
    #pragma unroll
    for (int ch = 0; ch < 4; ++ch) {
      const float* p = qp + ch * 16 + b5 * 8;
      float4 x0 = *(const float4*)(p);
      float4 x1 = *(const float4*)(p + 4);
      u32x4 qw = {cvtpk(x0.x * QSCALE, x0.y * QSCALE),
                  cvtpk(x0.z * QSCALE, x0.w * QSCALE),
                  cvtpk(x1.x * QSCALE, x1.y * QSCALE),
                  cvtpk(x1.z * QSCALE, x1.w * QSCALE)};
      qh[ch] = __builtin_bit_cast(u16x8, qw);
    }
  }

  // fragment base pointers (lane-resolved)
  const unsigned short* kp0 = Kf + (((long)b * 128 + (kv0 >> 5)) * 4) * 512 + lane * 8;
  const unsigned short* vp0 = Vf + (((long)b * 64 + (kv0 >> 6)) * 8) * 512 + lane * 8;

  f32x16 O0 = {0,0,0,0,0,0,0,0,0,0,0,0,0,0,0,0};
  f32x16 O1 = {0,0,0,0,0,0,0,0,0,0,0,0,0,0,0,0};
  float m = -INFINITY, lsum = 0.0f;          // lsum lane-local (own 32 keys)

  for (int t = 0; t < NT; ++t) {
    const unsigned short* kp = kp0 + (long)t * 4096;   // 2 kb32 * 4ch * 512
    const unsigned short* vp = vp0 + (long)t * 4096;   // 2 dh * 4 ks * 512

    // ---- K fragments (8 x dwordx4 from L2) --------------------------------
    u16x8 kf00 = *(const u16x8*)(kp +    0), kf01 = *(const u16x8*)(kp +  512);
    u16x8 kf02 = *(const u16x8*)(kp + 1024), kf03 = *(const u16x8*)(kp + 1536);
    u16x8 kf10 = *(const u16x8*)(kp + 2048), kf11 = *(const u16x8*)(kp + 2560);
    u16x8 kf12 = *(const u16x8*)(kp + 3072), kf13 = *(const u16x8*)(kp + 3584);

    // ---- QK^T swapped: sc[h] row=key=32h+(r&3)+8*(r>>2)+4*b5, col=q=l5 ----
    f32x16 sc0 = {0,0,0,0,0,0,0,0,0,0,0,0,0,0,0,0};
    f32x16 sc1 = {0,0,0,0,0,0,0,0,0,0,0,0,0,0,0,0};
    __builtin_amdgcn_s_setprio(1);
    sc0 = MFMA32(kf00, qh[0], sc0);  sc1 = MFMA32(kf10, qh[0], sc1);
    sc0 = MFMA32(kf01, qh[1], sc0);  sc1 = MFMA32(kf11, qh[1], sc1);
    sc0 = MFMA32(kf02, qh[2], sc0);  sc1 = MFMA32(kf12, qh[2], sc1);
    sc0 = MFMA32(kf03, qh[3], sc0);  sc1 = MFMA32(kf13, qh[3], sc1);
    __builtin_amdgcn_s_setprio(0);

    // ---- V fragments: issue early so latency hides under softmax ----------
    u16x8 vf00 = *(const u16x8*)(vp +    0), vf01 = *(const u16x8*)(vp +  512);
    u16x8 vf02 = *(const u16x8*)(vp + 1024), vf03 = *(const u16x8*)(vp + 1536);
    u16x8 vf10 = *(const u16x8*)(vp + 2048), vf11 = *(const u16x8*)(vp + 2560);
    u16x8 vf12 = *(const u16x8*)(vp + 3072), vf13 = *(const u16x8*)(vp + 3584);

    // ---- online softmax: tree max, lane-local, defer-max ------------------
    float tmx[16];
    #pragma unroll
    for (int r = 0; r < 16; ++r) tmx[r] = fmaxf(sc0[r], sc1[r]);
    #pragma unroll
    for (int r = 0; r < 8; ++r) tmx[r] = fmaxf(tmx[r], tmx[r + 8]);
    #pragma unroll
    for (int r = 0; r < 4; ++r) tmx[r] = fmaxf(tmx[r], tmx[r + 4]);
    const float smax_loc = fmaxf(fmaxf(tmx[0], tmx[1]), fmaxf(tmx[2], tmx[3]));

    if (!__all(smax_loc <= m + 8.0f)) {
      float a, bq;
      xswap32f(smax_loc, a, bq);               // uniform-per-q max
      const float mn = fmaxf(m, fmaxf(a, bq));
      const float fs = EXP2F(m - mn);          // exp2(-inf)=0 on first iter
      m = mn;
      lsum *= fs;
      #pragma unroll
      for (int r = 0; r < 16; ++r) { O0[r] *= fs; O1[r] *= fs; }
    }

    float p0[16], p1[16];
    #pragma unroll
    for (int r = 0; r < 16; ++r) {
      p0[r] = EXP2F(sc0[r] - m);
      p1[r] = EXP2F(sc1[r] - m);
    }
    {
      float u[16];
      #pragma unroll
      for (int r = 0; r < 16; ++r) u[r] = p0[r] + p1[r];
      #pragma unroll
      for (int r = 0; r < 8; ++r) u[r] += u[r + 8];
      #pragma unroll
      for (int r = 0; r < 4; ++r) u[r] += u[r + 4];
      lsum += (u[0] + u[1]) + (u[2] + u[3]);
    }

    // ---- P -> bf16 B-fragments via cvt_pk + permlane32_swap ---------------
    auto pack8 = [&](float a0, float a1, float a2, float a3,
                     float a4, float a5, float a6, float a7) -> u16x8 {
      unsigned int x0w = cvtpk(a0, a1), x1w = cvtpk(a2, a3);
      unsigned int y0w = cvtpk(a4, a5), y1w = cvtpk(a6, a7);
      plswap(x0w, y0w);
      plswap(x1w, y1w);
      u32x4 hw = {x0w, x1w, y0w, y1w};
      return __builtin_bit_cast(u16x8, hw);
    };
    u16x8 pb[4];
    pb[0] = pack8(p0[0], p0[1], p0[2],  p0[3],  p0[4],  p0[5],  p0[6],  p0[7]);
    pb[1] = pack8(p0[8], p0[9], p0[10], p0[11], p0[12], p0[13], p0[14], p0[15]);
    pb[2] = pack8(p1[0], p1[1], p1[2],  p1[3],  p1[4],  p1[5],  p1[6],  p1[7]);
    pb[3] = pack8(p1[8], p1[9], p1[10], p1[11], p1[12], p1[13], p1[14], p1[15]);

    // ---- PV: O^T[d][q] += V^T * P^T, two interleaved 4-chains -------------
    __builtin_amdgcn_s_setprio(1);
    O0 = MFMA32(vf00, pb[0], O0);  O1 = MFMA32(vf10, pb[0], O1);
    O0 = MFMA32(vf01, pb[1], O0);  O1 = MFMA32(vf11, pb[1], O1);
    O0 = MFMA32(vf02, pb[2], O0);  O1 = MFMA32(vf12, pb[2], O1);
    O0 = MFMA32(vf03, pb[3], O0);  O1 = MFMA32(vf13, pb[3], O1);
    __builtin_amdgcn_s_setprio(0);
  }

  // ---- combine lane-local lsum across the lane^32 split -------------------
  {
    float la, lb;
    xswap32f(lsum, la, lb);
    lsum = la + lb;
  }

  // ---- transpose O^T via per-wave LDS region, write partials --------------
  float* tbp = &tb[wave][0];
  #pragma unroll
  for (int mt = 0; mt < 2; ++mt) {
    #pragma unroll
    for (int r = 0; r < 16; ++r) {
      int d = mt * 32 + (r & 3) + ((r >> 2) << 3) + (b5 << 2);
      float val = mt ? O1[r] : O0[r];
      tbp[l5 * 64 + ((((d >> 2) ^ (l5 & 15)) << 2) | (d & 3))] = val;
    }
  }
  __builtin_amdgcn_s_waitcnt(0);   // same-wave ds_write -> ds_read ordering
  #pragma unroll
  for (int L = 0; L < 8; ++L) {
    int row = L * 4 + (lane >> 4);
    int cb  = lane & 15;
    float4 val = *(const float4*)&tbp[row * 64 + ((cb ^ (row & 15)) << 2)];
    long qg = (long)b * SEQ + qrow0 + row;
    *(float4*)(Opart + ((long)split * NQ + qg) * DIM + cb * 4) = val;
  }
  if (lane < 32) {
    long qg = (long)b * SEQ + qrow0 + lane;
    Mpart[(long)split * NQ + qg] = m;
    Lpart[(long)split * NQ + qg] = lsum;
  }
}

// ---------------- merge KV-split partials ----------------------------------
template<int NS>
__global__ __launch_bounds__(256) void merge_kernel(
    const float* __restrict__ Opart, const float* __restrict__ Mpart,
    const float* __restrict__ Lpart, float* __restrict__ Out) {
  int idx = blockIdx.x * 256 + threadIdx.x;  // over NQ*16
  int bq = idx >> 4;
  int d4 = (idx & 15) << 2;
  float ms[NS];
  float M = -INFINITY;
  #pragma unroll
  for (int s = 0; s < NS; ++s) { ms[s] = Mpart[s * NQ + bq]; M = fmaxf(M, ms[s]); }
  float L = 0.0f;
  float4 acc = {0, 0, 0, 0};
  #pragma unroll
  for (int s = 0; s < NS; ++s) {
    float w = EXP2F(ms[s] - M);
    L += w * Lpart[s * NQ + bq];
    float4 o = *(const float4*)(Opart + ((long)(s * NQ + bq)) * DIM + d4);
    acc.x += w * o.x; acc.y += w * o.y; acc.z += w * o.z; acc.w += w * o.w;
  }
  float inv = 1.0f / L;
  float4 r = {acc.x * inv, acc.y * inv, acc.z * inv, acc.w * inv};
  *(float4*)(Out + (long)bq * DIM + d4) = r;
}

extern "C" void kernel_launch(void* const* d_in, const int* in_sizes, int n_in,
                              void* d_out, int out_size, void* d_ws, size_t ws_size,
                              hipStream_t stream) {
  const float* Q = (const float*)d_in[0];
  const float* K = (const float*)d_in[1];
  const float* V = (const float*)d_in[2];
  float* Out = (float*)d_out;

  // ws: [Kf|Vf] bf16 fragment-ordered (4 MB) + Opart (NS*4MB) + M/L
  unsigned short* w16 = (unsigned short*)d_ws;
  unsigned short* Kf  = w16;
  unsigned short* Vf  = w16 + 1048576;
  float* wsf = (float*)(w16 + 2097152);

  const size_t need8 = (size_t)4 * 1024 * 1024 + (size_t)8 * NQ * DIM * 4
                     + (size_t)2 * 8 * NQ * 4;
  const int ns = (ws_size >= need8) ? 8 : 4;

  prep_kernel<<<dim3(256), dim3(256), 0, stream>>>(K, V, Kf, Vf);
  if (ns == 8) {
    float* Opart = wsf;
    float* Mpart = wsf + (size_t)8 * NQ * DIM;
    float* Lpart = Mpart + 8 * NQ;
    attn_kernel<8><<<dim3(1024), dim3(256), 0, stream>>>(Q, Kf, Vf, Opart, Mpart, Lpart);
    merge_kernel<8><<<dim3(1024), dim3(256), 0, stream>>>(Opart, Mpart, Lpart, Out);
  } else {
    float* Opart = wsf;
    float* Mpart = wsf + (size_t)4 * NQ * DIM;
    float* Lpart = Mpart + 4 * NQ;
    attn_kernel<4><<<dim3(512), dim3(256), 0, stream>>>(Q, Kf, Vf, Opart, Mpart, Lpart);
    merge_kernel<4><<<dim3(1024), dim3(256), 0, stream>>>(Opart, Mpart, Lpart, Out);
  }
}

// Round 8
// 46.784 us; speedup vs baseline: 1.1863x; 1.1863x over previous
//
#include <hip/hip_runtime.h>

// AttentionHead: B=4, S=4096, D=64, fp32 in/out.
// R8: fragment-order LDS staging. Prep writes K/V^T as MFMA-fragment 1KB
// blocks (R7, verified). attn stages 16 blocks/iter/WG into LDS once
// (4x L2-traffic cut vs R7), all LDS reads are base+lane*16 with immediate
// block offsets — no swizzle, no address math, conflict-free b128.
// 2-phase: STAGE(t+1) issued before compute(t), drained at the barrier.

#define BATCH 4
#define SEQ   4096
#define DIM   64
#define KVB   64
#define NQ    16384                  // BATCH*SEQ
#define QSCALE 0.18033688011112042f  // (1/sqrt(64)) * log2(e); all exps are exp2

typedef float f32x16 __attribute__((ext_vector_type(16)));
typedef unsigned short u16x8 __attribute__((ext_vector_type(8)));
typedef unsigned int   u32x4 __attribute__((ext_vector_type(4)));
typedef unsigned int   u32x2 __attribute__((ext_vector_type(2)));

#define MFMA32(a, b, c) __builtin_amdgcn_mfma_f32_32x32x16_bf16((a), (b), (c), 0, 0, 0)
#define EXP2F(x) __builtin_amdgcn_exp2f(x)

__device__ __forceinline__ void plswap(unsigned int& a, unsigned int& b) {
  u32x2 r = __builtin_amdgcn_permlane32_swap(a, b, false, false);
  a = r[0]; b = r[1];
}
__device__ __forceinline__ void xswap32f(float x, float& a, float& b) {
  unsigned int u = __float_as_uint(x), v = u;
  plswap(u, v);
  a = __uint_as_float(u); b = __uint_as_float(v);
}

__device__ __forceinline__ unsigned short f2bf(float x) {
  unsigned int u = __float_as_uint(x);
  return (unsigned short)((u + 0x7fffu + ((u >> 16) & 1u)) >> 16);   // RNE
}
__device__ __forceinline__ unsigned int cvtpk(float a, float b) {  // lo=a, hi=b
  unsigned int r;
  asm("v_cvt_pk_bf16_f32 %0, %1, %2" : "=v"(r) : "v"(a), "v"(b));
  return r;
}

// ---------------- prep: K,V -> fragment-ordered bf16 (verified in R7) -------
// Kf block (b, kb32, ch): elem l*8+j = K[b][kb32*32+(l&31)][ch*16+(l>>5)*8+j]
// Vf block (b, kb64, dh, ks): elem l*8+j = V[b][kb64*64+ks*16+(l>>5)*8+j][dh*32+(l&31)]
__global__ __launch_bounds__(256) void prep_kernel(
    const float* __restrict__ K, const float* __restrict__ V,
    unsigned short* __restrict__ Kf, unsigned short* __restrict__ Vf) {
  __shared__ float tk[64][65];
  __shared__ float tv[64][65];
  const int t = threadIdx.x;
  const int b = blockIdx.x >> 6;
  const int s0 = (blockIdx.x & 63) << 6;
  #pragma unroll
  for (int r = 0; r < 4; ++r) {
    const int s_loc = r * 16 + (t >> 4);
    const int d0 = (t & 15) << 2;
    const long base = ((long)b * SEQ + s0 + s_loc) * DIM + d0;
    const float4 kv = *(const float4*)(K + base);
    const float4 vv = *(const float4*)(V + base);
    tk[s_loc][d0 + 0] = kv.x; tk[s_loc][d0 + 1] = kv.y;
    tk[s_loc][d0 + 2] = kv.z; tk[s_loc][d0 + 3] = kv.w;
    tv[s_loc][d0 + 0] = vv.x; tv[s_loc][d0 + 1] = vv.y;
    tv[s_loc][d0 + 2] = vv.z; tv[s_loc][d0 + 3] = vv.w;
  }
  __syncthreads();
  const int l  = t >> 2;           // 0..63 (fragment lane)
  const int j0 = (t & 3) << 1;     // 0,2,4,6
  const int l5 = l & 31, b5 = l >> 5;
  #pragma unroll
  for (int kh = 0; kh < 2; ++kh) {
    #pragma unroll
    for (int ch = 0; ch < 4; ++ch) {
      const int key = kh * 32 + l5;
      const int d   = ch * 16 + b5 * 8 + j0;
      ushort2 w;
      w.x = f2bf(tk[key][d]);
      w.y = f2bf(tk[key][d + 1]);
      const long kb32 = (s0 >> 5) + kh;
      const long off = (((long)b * 128 + kb32) * 4 + ch) * 512 + 2 * t;
      *(ushort2*)(Kf + off) = w;
    }
  }
  #pragma unroll
  for (int dh = 0; dh < 2; ++dh) {
    #pragma unroll
    for (int ks = 0; ks < 4; ++ks) {
      const int key0 = ks * 16 + b5 * 8 + j0;
      const int d    = dh * 32 + l5;
      ushort2 w;
      w.x = f2bf(tv[key0][d]);
      w.y = f2bf(tv[key0 + 1][d]);
      const long kb64 = (s0 >> 6);
      const long off = ((((long)b * 64 + kb64) * 2 + dh) * 4 + ks) * 512 + 2 * t;
      *(ushort2*)(Vf + off) = w;
    }
  }
}

// ---------------- attention main kernel ------------------------------------
template<int NS>
__global__ __launch_bounds__(256, 4) void attn_kernel(
    const float* __restrict__ Q,
    const unsigned short* __restrict__ Kf, const unsigned short* __restrict__ Vf,
    float* __restrict__ Opart, float* __restrict__ Mpart, float* __restrict__ Lpart) {

  // 2 bufs x 16 fragment blocks (K: 0-7, V: 8-15) x 1KB = 32 KB
  __shared__ __align__(16) unsigned short tiles[2][16 * 512];

  constexpr int SPL = SEQ / NS;
  constexpr int NT  = SPL / KVB;
  constexpr int NWG = 4 * NS * 32;
  constexpr int CPX = NWG / 8;

  const int raw = blockIdx.x;
  const int bid = (raw & 7) * CPX + (raw >> 3);   // XCD-contiguous, bijective
  const int b     = bid / (NS * 32);
  const int rem   = bid % (NS * 32);
  const int split = rem >> 5;
  const int qblk  = rem & 31;

  const int tid  = threadIdx.x;
  const int wave = tid >> 6;
  const int lane = tid & 63;
  const int l5   = lane & 31;
  const int b5   = lane >> 5;

  const int qrow0 = qblk * 128 + wave * 32;
  const int kv0   = split * SPL;

  // ---- Q fragments: q row = l5; frag[ch] elem j <-> d = 16*ch + 8*b5 + j ----
  u16x8 qh[4];
  {
    const float* qp = Q + ((long)b * SEQ + qrow0 + l5) * DIM;
    #pragma unroll
    for (int ch = 0; ch < 4; ++ch) {
      const float* p = qp + ch * 16 + b5 * 8;
      float4 x0 = *(const float4*)(p);
      float4 x1 = *(const float4*)(p + 4);
      u32x4 qw = {cvtpk(x0.x * QSCALE, x0.y * QSCALE),
                  cvtpk(x0.z * QSCALE, x0.w * QSCALE),
                  cvtpk(x1.x * QSCALE, x1.y * QSCALE),
                  cvtpk(x1.z * QSCALE, x1.w * QSCALE)};
      qh[ch] = __builtin_bit_cast(u16x8, qw);
    }
  }

  // ---- staging roles: wave>>1 selects K/V, wave&1 selects 4-block group ----
  const int kvrole = wave >> 1;            // 0: K blocks 0-7, 1: V blocks 8-15
  const int lb     = (wave & 1) * 4;       // block group within role
  const unsigned short* gsrc =
      kvrole ? Vf + (((long)b * 64 + (kv0 >> 6)) * 8) * 512
             : Kf + (((long)b * 128 + (kv0 >> 5)) * 4) * 512;

  auto stage = [&](int buf, int t) {
    const unsigned short* s = gsrc + (long)t * 4096 + lb * 512 + lane * 8;
    unsigned short* d = &tiles[buf][(kvrole * 8 + lb) * 512];
    #pragma unroll
    for (int i = 0; i < 4; ++i)
      __builtin_amdgcn_global_load_lds(
          (__attribute__((address_space(1))) void*)(s + i * 512),
          (__attribute__((address_space(3))) void*)(d + i * 512), 16, 0, 0);
  };

  stage(0, 0);
  __syncthreads();

  f32x16 O0 = {0,0,0,0,0,0,0,0,0,0,0,0,0,0,0,0};
  f32x16 O1 = {0,0,0,0,0,0,0,0,0,0,0,0,0,0,0,0};
  float m = -INFINITY, lsum = 0.0f;          // lsum lane-local (own 32 keys)

  for (int t = 0; t < NT; ++t) {
    const int buf = t & 1;
    if (t + 1 < NT) stage(buf ^ 1, t + 1);   // async; drained by end barrier

    // fragment reads: base + lane*16 bytes, block n at immediate offset n KB
    const u16x8* fb = (const u16x8*)(&tiles[buf][0]) + lane;

    // ---- QK^T swapped: sc[h] row=key=32h+(r&3)+8*(r>>2)+4*b5, col=q=l5 ----
    f32x16 sc0 = {0,0,0,0,0,0,0,0,0,0,0,0,0,0,0,0};
    f32x16 sc1 = {0,0,0,0,0,0,0,0,0,0,0,0,0,0,0,0};
    __builtin_amdgcn_s_setprio(1);
    sc0 = MFMA32(fb[0 * 64], qh[0], sc0);  sc1 = MFMA32(fb[4 * 64], qh[0], sc1);
    sc0 = MFMA32(fb[1 * 64], qh[1], sc0);  sc1 = MFMA32(fb[5 * 64], qh[1], sc1);
    sc0 = MFMA32(fb[2 * 64], qh[2], sc0);  sc1 = MFMA32(fb[6 * 64], qh[2], sc1);
    sc0 = MFMA32(fb[3 * 64], qh[3], sc0);  sc1 = MFMA32(fb[7 * 64], qh[3], sc1);
    __builtin_amdgcn_s_setprio(0);

    // ---- online softmax: tree max, lane-local, defer-max ------------------
    float tmx[16];
    #pragma unroll
    for (int r = 0; r < 16; ++r) tmx[r] = fmaxf(sc0[r], sc1[r]);
    #pragma unroll
    for (int r = 0; r < 8; ++r) tmx[r] = fmaxf(tmx[r], tmx[r + 8]);
    #pragma unroll
    for (int r = 0; r < 4; ++r) tmx[r] = fmaxf(tmx[r], tmx[r + 4]);
    const float smax_loc = fmaxf(fmaxf(tmx[0], tmx[1]), fmaxf(tmx[2], tmx[3]));

    if (!__all(smax_loc <= m + 8.0f)) {
      float a, bq;
      xswap32f(smax_loc, a, bq);               // uniform-per-q max
      const float mn = fmaxf(m, fmaxf(a, bq));
      const float fs = EXP2F(m - mn);          // exp2(-inf)=0 on first iter
      m = mn;
      lsum *= fs;
      #pragma unroll
      for (int r = 0; r < 16; ++r) { O0[r] *= fs; O1[r] *= fs; }
    }

    float p0[16], p1[16];
    #pragma unroll
    for (int r = 0; r < 16; ++r) {
      p0[r] = EXP2F(sc0[r] - m);
      p1[r] = EXP2F(sc1[r] - m);
    }
    {
      float u[16];
      #pragma unroll
      for (int r = 0; r < 16; ++r) u[r] = p0[r] + p1[r];
      #pragma unroll
      for (int r = 0; r < 8; ++r) u[r] += u[r + 8];
      #pragma unroll
      for (int r = 0; r < 4; ++r) u[r] += u[r + 4];
      lsum += (u[0] + u[1]) + (u[2] + u[3]);
    }

    // ---- P -> bf16 B-fragments via cvt_pk + permlane32_swap ---------------
    auto pack8 = [&](float a0, float a1, float a2, float a3,
                     float a4, float a5, float a6, float a7) -> u16x8 {
      unsigned int x0w = cvtpk(a0, a1), x1w = cvtpk(a2, a3);
      unsigned int y0w = cvtpk(a4, a5), y1w = cvtpk(a6, a7);
      plswap(x0w, y0w);
      plswap(x1w, y1w);
      u32x4 hw = {x0w, x1w, y0w, y1w};
      return __builtin_bit_cast(u16x8, hw);
    };
    u16x8 pb[4];
    pb[0] = pack8(p0[0], p0[1], p0[2],  p0[3],  p0[4],  p0[5],  p0[6],  p0[7]);
    pb[1] = pack8(p0[8], p0[9], p0[10], p0[11], p0[12], p0[13], p0[14], p0[15]);
    pb[2] = pack8(p1[0], p1[1], p1[2],  p1[3],  p1[4],  p1[5],  p1[6],  p1[7]);
    pb[3] = pack8(p1[8], p1[9], p1[10], p1[11], p1[12], p1[13], p1[14], p1[15]);

    // ---- PV: V blocks 8-15; O0 uses dh=0 (8..11), O1 dh=1 (12..15) --------
    __builtin_amdgcn_s_setprio(1);
    O0 = MFMA32(fb[ 8 * 64], pb[0], O0);  O1 = MFMA32(fb[12 * 64], pb[0], O1);
    O0 = MFMA32(fb[ 9 * 64], pb[1], O0);  O1 = MFMA32(fb[13 * 64], pb[1], O1);
    O0 = MFMA32(fb[10 * 64], pb[2], O0);  O1 = MFMA32(fb[14 * 64], pb[2], O1);
    O0 = MFMA32(fb[11 * 64], pb[3], O0);  O1 = MFMA32(fb[15 * 64], pb[3], O1);
    __builtin_amdgcn_s_setprio(0);

    __syncthreads();   // drains staged t+1 loads + all LDS reads of buf
  }

  // ---- combine lane-local lsum across the lane^32 split -------------------
  {
    float la, lb2;
    xswap32f(lsum, la, lb2);
    lsum = la + lb2;
  }

  // ---- transpose O^T via per-wave LDS region, write partials --------------
  float* tbp = (float*)(&tiles[0][0]) + wave * 2048;
  #pragma unroll
  for (int mt = 0; mt < 2; ++mt) {
    #pragma unroll
    for (int r = 0; r < 16; ++r) {
      int d = mt * 32 + (r & 3) + ((r >> 2) << 3) + (b5 << 2);
      float val = mt ? O1[r] : O0[r];
      tbp[l5 * 64 + ((((d >> 2) ^ (l5 & 15)) << 2) | (d & 3))] = val;
    }
  }
  __builtin_amdgcn_s_waitcnt(0);   // same-wave ds_write -> ds_read ordering
  #pragma unroll
  for (int L = 0; L < 8; ++L) {
    int row = L * 4 + (lane >> 4);
    int cb  = lane & 15;
    float4 val = *(const float4*)&tbp[row * 64 + ((cb ^ (row & 15)) << 2)];
    long qg = (long)b * SEQ + qrow0 + row;
    *(float4*)(Opart + ((long)split * NQ + qg) * DIM + cb * 4) = val;
  }
  if (lane < 32) {
    long qg = (long)b * SEQ + qrow0 + lane;
    Mpart[(long)split * NQ + qg] = m;
    Lpart[(long)split * NQ + qg] = lsum;
  }
}

// ---------------- merge KV-split partials ----------------------------------
template<int NS>
__global__ __launch_bounds__(256) void merge_kernel(
    const float* __restrict__ Opart, const float* __restrict__ Mpart,
    const float* __restrict__ Lpart, float* __restrict__ Out) {
  int idx = blockIdx.x * 256 + threadIdx.x;  // over NQ*16
  int bq = idx >> 4;
  int d4 = (idx & 15) << 2;
  float ms[NS];
  float M = -INFINITY;
  #pragma unroll
  for (int s = 0; s < NS; ++s) { ms[s] = Mpart[s * NQ + bq]; M = fmaxf(M, ms[s]); }
  float L = 0.0f;
  float4 acc = {0, 0, 0, 0};
  #pragma unroll
  for (int s = 0; s < NS; ++s) {
    float w = EXP2F(ms[s] - M);
    L += w * Lpart[s * NQ + bq];
    float4 o = *(const float4*)(Opart + ((long)(s * NQ + bq)) * DIM + d4);
    acc.x += w * o.x; acc.y += w * o.y; acc.z += w * o.z; acc.w += w * o.w;
  }
  float inv = 1.0f / L;
  float4 r = {acc.x * inv, acc.y * inv, acc.z * inv, acc.w * inv};
  *(float4*)(Out + (long)bq * DIM + d4) = r;
}

extern "C" void kernel_launch(void* const* d_in, const int* in_sizes, int n_in,
                              void* d_out, int out_size, void* d_ws, size_t ws_size,
                              hipStream_t stream) {
  const float* Q = (const float*)d_in[0];
  const float* K = (const float*)d_in[1];
  const float* V = (const float*)d_in[2];
  float* Out = (float*)d_out;

  // ws: [Kf|Vf] bf16 fragment-ordered (4 MB) + Opart (NS*4MB) + M/L
  unsigned short* w16 = (unsigned short*)d_ws;
  unsigned short* Kf  = w16;
  unsigned short* Vf  = w16 + 1048576;
  float* wsf = (float*)(w16 + 2097152);

  const size_t need8 = (size_t)4 * 1024 * 1024 + (size_t)8 * NQ * DIM * 4
                     + (size_t)2 * 8 * NQ * 4;
  const int ns = (ws_size >= need8) ? 8 : 4;

  prep_kernel<<<dim3(256), dim3(256), 0, stream>>>(K, V, Kf, Vf);
  if (ns == 8) {
    float* Opart = wsf;
    float* Mpart = wsf + (size_t)8 * NQ * DIM;
    float* Lpart = Mpart + 8 * NQ;
    attn_kernel<8><<<dim3(1024), dim3(256), 0, stream>>>(Q, Kf, Vf, Opart, Mpart, Lpart);
    merge_kernel<8><<<dim3(1024), dim3(256), 0, stream>>>(Opart, Mpart, Lpart, Out);
  } else {
    float* Opart = wsf;
    float* Mpart = wsf + (size_t)4 * NQ * DIM;
    float* Lpart = Mpart + 4 * NQ;
    attn_kernel<4><<<dim3(512), dim3(256), 0, stream>>>(Q, Kf, Vf, Opart, Mpart, Lpart);
    merge_kernel<4><<<dim3(1024), dim3(256), 0, stream>>>(Opart, Mpart, Lpart, Out);
  }
}